// Round 1
// baseline (495.421 us; speedup 1.0000x reference)
//
#include <hip/hip_runtime.h>

#define MAXIT 100
#define TARGET 30.0f
#define WEIGHT 0.1f

__global__ __launch_bounds__(256) void escape_partial(
    const float* __restrict__ crg, const float* __restrict__ cig,
    float* __restrict__ partial, int n) {
  int idx = blockIdx.x * 256 + threadIdx.x;
  float nd = 0.0f;
  if (idx < n) {
    float cr = crg[idx];
    float ci = cig[idx];
    float zr = 0.0f, zi = 0.0f;
    float iters = 0.0f;
    for (int i = 0; i < MAXIT; ++i) {
      float zr2 = zr * zr;
      float zi2 = zi * zi;
      float zr_new = zr2 - zi2 + cr;
      float zi_new = 2.0f * zr * zi + ci;
      float mag = zr_new * zr_new + zi_new * zi_new;
      float dr = fabsf(zr_new - zr);
      float di = fabsf(zi_new - zi);
      // cycle detection first (matches reference: in_cycle wins over escape)
      if ((dr < 1e-6f) && (di < 1e-6f) && (i > 0)) { iters = (float)MAXIT; break; }
      if (mag > 4.0f) { iters = (float)(i + 1); break; }
      zr = zr_new; zi = zi_new;
    }
    if (iters == 0.0f) iters = (float)MAXIT;  // never escaped, never cycled
    nd = fabsf(iters - TARGET) * (1.0f / TARGET);
  }
  // wave64 reduce
  for (int off = 32; off > 0; off >>= 1) nd += __shfl_down(nd, off, 64);
  __shared__ float sm[4];
  int lane = threadIdx.x & 63;
  int wid  = threadIdx.x >> 6;
  if (lane == 0) sm[wid] = nd;
  __syncthreads();
  if (threadIdx.x == 0) partial[blockIdx.x] = sm[0] + sm[1] + sm[2] + sm[3];
}

__global__ __launch_bounds__(256) void reduce_final(
    const float* __restrict__ partial, int nparts,
    float* __restrict__ out, float scale) {
  double s = 0.0;
  for (int i = threadIdx.x; i < nparts; i += 256) s += (double)partial[i];
  for (int off = 32; off > 0; off >>= 1) s += __shfl_down(s, off, 64);
  __shared__ double sm[4];
  int lane = threadIdx.x & 63;
  int wid  = threadIdx.x >> 6;
  if (lane == 0) sm[wid] = s;
  __syncthreads();
  if (threadIdx.x == 0)
    out[0] = (float)((sm[0] + sm[1] + sm[2] + sm[3]) * (double)scale);
}

extern "C" void kernel_launch(void* const* d_in, const int* in_sizes, int n_in,
                              void* d_out, int out_size, void* d_ws, size_t ws_size,
                              hipStream_t stream) {
  const float* cr = (const float*)d_in[0];
  const float* ci = (const float*)d_in[1];
  int n = in_sizes[0];
  int blocks = (n + 255) / 256;
  float* partial = (float*)d_ws;
  escape_partial<<<blocks, 256, 0, stream>>>(cr, ci, partial, n);
  reduce_final<<<1, 256, 0, stream>>>(partial, blocks, (float*)d_out,
                                      WEIGHT / (float)n);
}

// Round 2
// 336.678 us; speedup vs baseline: 1.4715x; 1.4715x over previous
//
#include <hip/hip_runtime.h>

#define MAXIT 100
#define K1 20           // phase-A iterations before block-level survivor compaction
#define TARGET 30.0f
#define WEIGHT 0.1f
#define EPS 1e-6f

__global__ __launch_bounds__(256) void escape_partial(
    const float* __restrict__ crg, const float* __restrict__ cig,
    float* __restrict__ partial, int n) {
  const int tid  = threadIdx.x;
  const int idx  = blockIdx.x * 256 + tid;
  const int lane = tid & 63;
  const int wid  = tid >> 6;

  __shared__ float sZr[256], sZi[256], sCr[256], sCi[256];
  __shared__ int   wcnt[4];
  __shared__ float sm[4];

  float nd_sum = 0.0f;
  float zr = 0.0f, zi = 0.0f, cr = 0.0f, ci = 0.0f;
  float iters = 0.0f;          // 0 == still active (real values are >= 1)
  const bool valid = idx < n;

  if (valid) {
    cr = crg[idx]; ci = cig[idx];
    // iteration i=0 peeled: z1 = c; cycle check skipped per reference (i > 0)
    zr = cr; zi = ci;
    if (__builtin_fmaf(cr, cr, ci * ci) > 4.0f) {
      iters = 1.0f;
    } else {
      for (int i = 1; i < K1; ++i) {
        float zi2    = zi * zi;
        float zr_new = __builtin_fmaf(zr, zr, cr - zi2);
        float zi_new = __builtin_fmaf(zr + zr, zi, ci);
        float mag    = __builtin_fmaf(zr_new, zr_new, zi_new * zi_new);
        bool cyc = (fabsf(zr_new - zr) < EPS) & (fabsf(zi_new - zi) < EPS);
        bool esc = mag > 4.0f;
        if (cyc | esc) {            // cycle wins over escape, matching reference
          iters = cyc ? 100.0f : (float)(i + 1);
          break;
        }
        zr = zr_new; zi = zi_new;
      }
    }
    if (iters != 0.0f) nd_sum = fabsf(iters - TARGET) * (1.0f / TARGET);
  }

  // ---- block-level survivor compaction into LDS (packed continuation) ----
  const bool active = valid && (iters == 0.0f);
  unsigned long long bal = __ballot(active);
  if (lane == 0) wcnt[wid] = __popcll(bal);
  __syncthreads();
  int base = 0;
  for (int w = 0; w < wid; ++w) base += wcnt[w];
  const int S = wcnt[0] + wcnt[1] + wcnt[2] + wcnt[3];
  if (active) {
    int pos = base + __popcll(bal & ((1ull << lane) - 1ull));
    sZr[pos] = zr; sZi[pos] = zi; sCr[pos] = cr; sCi[pos] = ci;
  }
  __syncthreads();

  if (tid < S) {
    float azr = sZr[tid], azi = sZi[tid], acr = sCr[tid], aci = sCi[tid];
    float it2 = 0.0f;
    for (int i = K1; i < MAXIT; ++i) {
      float zi2    = azi * azi;
      float zr_new = __builtin_fmaf(azr, azr, acr - zi2);
      float zi_new = __builtin_fmaf(azr + azr, azi, aci);
      float mag    = __builtin_fmaf(zr_new, zr_new, zi_new * zi_new);
      bool cyc = (fabsf(zr_new - azr) < EPS) & (fabsf(zi_new - azi) < EPS);
      bool esc = mag > 4.0f;
      if (cyc | esc) {
        it2 = cyc ? 100.0f : (float)(i + 1);
        break;
      }
      azr = zr_new; azi = zi_new;
    }
    if (it2 == 0.0f) it2 = 100.0f;    // never escaped, never cycled
    nd_sum += fabsf(it2 - TARGET) * (1.0f / TARGET);
  }

  // ---- block reduction of nd_sum ----
  for (int off = 32; off > 0; off >>= 1) nd_sum += __shfl_down(nd_sum, off, 64);
  if (lane == 0) sm[wid] = nd_sum;
  __syncthreads();
  if (tid == 0) partial[blockIdx.x] = sm[0] + sm[1] + sm[2] + sm[3];
}

__global__ __launch_bounds__(256) void reduce_final(
    const float* __restrict__ partial, int nparts,
    float* __restrict__ out, float scale) {
  int i = blockIdx.x * 256 + threadIdx.x;
  float v = (i < nparts) ? partial[i] : 0.0f;
  for (int off = 32; off > 0; off >>= 1) v += __shfl_down(v, off, 64);
  __shared__ float sm[4];
  int lane = threadIdx.x & 63, wid = threadIdx.x >> 6;
  if (lane == 0) sm[wid] = v;
  __syncthreads();
  if (threadIdx.x == 0)
    atomicAdd(out, (sm[0] + sm[1] + sm[2] + sm[3]) * scale);
}

extern "C" void kernel_launch(void* const* d_in, const int* in_sizes, int n_in,
                              void* d_out, int out_size, void* d_ws, size_t ws_size,
                              hipStream_t stream) {
  const float* cr = (const float*)d_in[0];
  const float* ci = (const float*)d_in[1];
  int n = in_sizes[0];
  int blocks = (n + 255) / 256;
  float* partial = (float*)d_ws;

  hipMemsetAsync(d_out, 0, sizeof(float), stream);  // d_out is re-poisoned; atomic target
  escape_partial<<<blocks, 256, 0, stream>>>(cr, ci, partial, n);
  reduce_final<<<(blocks + 255) / 256, 256, 0, stream>>>(
      partial, blocks, (float*)d_out, WEIGHT / (float)n);
}

// Round 3
// 207.136 us; speedup vs baseline: 2.3918x; 1.6254x over previous
//
#include <hip/hip_runtime.h>

#define MAXIT  100
#define R0     10      // round-0 iterations (from global)
#define RSTEP  10      // iterations per LDS-compacted round
#define TARGET 30.0f
#define WEIGHT 0.1f
#define EPS    1e-6f
#define EPB    1024    // elements per block
#define TPB    256

__global__ __launch_bounds__(TPB) void escape_partial(
    const float* __restrict__ crg, const float* __restrict__ cig,
    float* __restrict__ partial, int n) {
  __shared__ float4 q[EPB];
  __shared__ int scount;
  __shared__ float sm[4];

  const int tid  = threadIdx.x;
  const int lane = tid & 63;
  const int wid  = tid >> 6;
  const int blockBase = blockIdx.x * EPB;

  float nd = 0.0f;

  // per-chunk survivor state (static indices only — no runtime-indexed arrays)
  float eZr[4], eZi[4], eCr[4], eCi[4];
  bool  eAl[4];

  // ---- round 0: iters [0, R0), source = global (coalesced) ----
  #pragma unroll
  for (int k = 0; k < 4; ++k) {
    eAl[k] = false;
    int idx = blockBase + k * TPB + tid;
    if (idx < n) {
      float c_r = crg[idx], c_i = cig[idx];
      float zr = 0.0f, zi = 0.0f;
      float fin = 0.0f;                    // 0 == still active
      for (int i = 0; i < R0; ++i) {
        float zr_new = __builtin_fmaf(zr, zr, c_r - zi * zi);
        float zi_new = __builtin_fmaf(zr + zr, zi, c_i);
        bool cyc = (i > 0) & (fabsf(zr_new - zr) < EPS) & (fabsf(zi_new - zi) < EPS);
        bool esc = __builtin_fmaf(zr_new, zr_new, zi_new * zi_new) > 4.0f;
        if (cyc | esc) { fin = cyc ? 100.0f : (float)(i + 1); break; }  // cycle wins
        zr = zr_new; zi = zi_new;
      }
      if (fin != 0.0f) nd += fabsf(fin - TARGET) * (1.0f / TARGET);
      else { eAl[k] = true; eZr[k] = zr; eZi[k] = zi; eCr[k] = c_r; eCi[k] = c_i; }
    }
  }

  if (tid == 0) scount = 0;
  __syncthreads();
  #pragma unroll
  for (int k = 0; k < 4; ++k) {            // ballot-compact append into LDS queue
    unsigned long long bal = __ballot(eAl[k]);
    int cnt = __popcll(bal);
    if (cnt) {
      int wbase = 0;
      if (lane == 0) wbase = atomicAdd(&scount, cnt);
      wbase = __shfl(wbase, 0, 64);
      if (eAl[k]) {
        int pos = wbase + __popcll(bal & ((1ull << lane) - 1ull));
        q[pos] = make_float4(eZr[k], eZi[k], eCr[k], eCi[k]);
      }
    }
  }
  __syncthreads();
  int S = scount;
  int rot = 0;

  // ---- LDS-compacted rounds: iters [base, base+RSTEP) ----
  for (int base = R0; base < MAXIT && S > 0; base += RSTEP) {
    rot = (rot + 64) & (TPB - 1);          // rotate idle tail across SIMDs
    const int effTid = (tid + rot) & (TPB - 1);
    #pragma unroll
    for (int k = 0; k < 4; ++k) {
      eAl[k] = false;
      int j = k * TPB + effTid;
      if (j < S) {
        float4 e = q[j];
        float zr = e.x, zi = e.y, c_r = e.z, c_i = e.w;
        float fin = 0.0f;
        for (int i = base; i < base + RSTEP; ++i) {
          float zr_new = __builtin_fmaf(zr, zr, c_r - zi * zi);
          float zi_new = __builtin_fmaf(zr + zr, zi, c_i);
          bool cyc = (fabsf(zr_new - zr) < EPS) & (fabsf(zi_new - zi) < EPS);
          bool esc = __builtin_fmaf(zr_new, zr_new, zi_new * zi_new) > 4.0f;
          if (cyc | esc) { fin = cyc ? 100.0f : (float)(i + 1); break; }
          zr = zr_new; zi = zi_new;
        }
        if (fin != 0.0f) nd += fabsf(fin - TARGET) * (1.0f / TARGET);
        else { eAl[k] = true; eZr[k] = zr; eZi[k] = zi; eCr[k] = c_r; eCi[k] = c_i; }
      }
    }
    __syncthreads();                       // all queue reads done
    if (tid == 0) scount = 0;
    __syncthreads();
    #pragma unroll
    for (int k = 0; k < 4; ++k) {          // in-place re-compaction
      unsigned long long bal = __ballot(eAl[k]);
      int cnt = __popcll(bal);
      if (cnt) {
        int wbase = 0;
        if (lane == 0) wbase = atomicAdd(&scount, cnt);
        wbase = __shfl(wbase, 0, 64);
        if (eAl[k]) {
          int pos = wbase + __popcll(bal & ((1ull << lane) - 1ull));
          q[pos] = make_float4(eZr[k], eZi[k], eCr[k], eCi[k]);
        }
      }
    }
    __syncthreads();
    S = scount;
  }

  // ---- leftovers after 100 iters (or cycle-trapped queue): iters = 100 ----
  {
    int mine = 0;
    #pragma unroll
    for (int k = 0; k < 4; ++k) if (k * TPB + tid < S) ++mine;
    nd += (float)mine * ((100.0f - TARGET) * (1.0f / TARGET));
  }

  // ---- block reduce ----
  for (int off = 32; off > 0; off >>= 1) nd += __shfl_down(nd, off, 64);
  if (lane == 0) sm[wid] = nd;
  __syncthreads();
  if (tid == 0) partial[blockIdx.x] = sm[0] + sm[1] + sm[2] + sm[3];
}

__global__ __launch_bounds__(256) void reduce_final(
    const float* __restrict__ partial, int nparts,
    float* __restrict__ out, float scale) {
  int i = blockIdx.x * 256 + threadIdx.x;
  float v = (i < nparts) ? partial[i] : 0.0f;
  for (int off = 32; off > 0; off >>= 1) v += __shfl_down(v, off, 64);
  __shared__ float sm[4];
  int lane = threadIdx.x & 63, wid = threadIdx.x >> 6;
  if (lane == 0) sm[wid] = v;
  __syncthreads();
  if (threadIdx.x == 0)
    atomicAdd(out, (sm[0] + sm[1] + sm[2] + sm[3]) * scale);
}

extern "C" void kernel_launch(void* const* d_in, const int* in_sizes, int n_in,
                              void* d_out, int out_size, void* d_ws, size_t ws_size,
                              hipStream_t stream) {
  const float* cr = (const float*)d_in[0];
  const float* ci = (const float*)d_in[1];
  int n = in_sizes[0];
  int blocks = (n + EPB - 1) / EPB;        // 8192 at N=8388608
  float* partial = (float*)d_ws;

  hipMemsetAsync(d_out, 0, sizeof(float), stream);
  escape_partial<<<blocks, TPB, 0, stream>>>(cr, ci, partial, n);
  reduce_final<<<(blocks + 255) / 256, 256, 0, stream>>>(
      partial, blocks, (float*)d_out, WEIGHT / (float)n);
}